// Round 3
// baseline (242.546 us; speedup 1.0000x reference)
//
#include <hip/hip_runtime.h>
#include <math.h>

#define B_    2
#define T_    2048
#define EMB_  128
#define NH_   8
#define M_    9
#define P_    36
#define GADD_ 2

// ---------------- Threefry-2x32 (jax PRNG) ----------------
__device__ __forceinline__ unsigned rotl32(unsigned x, int r){ return (x<<r)|(x>>(32-r)); }

struct U2 { unsigned x, y; };

__device__ __forceinline__ U2 tf2x32(U2 key, U2 ctr){
  unsigned ks0 = key.x, ks1 = key.y, ks2 = key.x ^ key.y ^ 0x1BD11BDAu;
  unsigned ks[3] = { ks0, ks1, ks2 };
  unsigned x0 = ctr.x + ks[0], x1 = ctr.y + ks[1];
  const int rotA[4] = {13,15,26,6}, rotB[4] = {17,29,16,24};
  #pragma unroll
  for (int r = 0; r < 5; ++r){
    const int* rr = (r & 1) ? rotB : rotA;
    #pragma unroll
    for (int i = 0; i < 4; ++i){ x0 += x1; x1 = rotl32(x1, rr[i]); x1 ^= x0; }
    x0 += ks[(r+1)%3];
    x1 += ks[(r+2)%3] + (unsigned)(r+1);
  }
  return { x0, x1 };
}

// jax.random.randint(jax.random.key(42), (B,T,M,GADD), 0, T) with the
// partitionable (default, JAX>=0.4.30) threefry path:
//   k1,k2 = split(key(42))          -> k2 = tf2x32((0,42), (0,1))
//   lower_bits = random_bits(k2)    -> per flat f: o = tf2x32(k2, (0,f)); bits = o.x^o.y
//   span=2048 (pow2, multiplier==0) -> value = bits & 2047
__device__ unsigned glob_rand(unsigned f){
  U2 k2 = tf2x32({0u, 42u}, {0u, 1u});
  U2 o  = tf2x32(k2, {0u, f});
  return (o.x ^ o.y) & (unsigned)(T_-1);
}

// ---------------- kernel 1: indices + weights ----------------
__global__ void idx_weights_kernel(const float* __restrict__ sp, const float* __restrict__ mvals,
                                   int* __restrict__ idx_out, float* __restrict__ w_out){
  const int bt = blockIdx.x;
  const int t  = bt & (T_-1);
  const int p  = threadIdx.x;
  __shared__ int   s_idx[P_];
  __shared__ float s_dens[P_][M_];
  __shared__ float s_col[M_];

  const float dil  = sp[0];
  const float xs   = sp[1] + 2.0f;                    // sigma_raw + SIGMA_BOOST
  const float sigma = xs + log1pf(expf(-xs)) + 1e-7f; // softplus + EPS

  if (p < P_){
    const int m = p >> 2, j = p & 3;
    const float mean = fminf(fmaxf((float)t + (float)(m-4)*dil, 0.f), (float)(T_-1));
    int id;
    if      (j == 0) id = (int)floorf(mean);
    else if (j == 1) id = min((int)floorf(mean) + 1, T_-1);
    else {
      const unsigned f = ((unsigned)bt * M_ + (unsigned)m) * GADD_ + (unsigned)(j-2);
      id = (int)glob_rand(f);
    }
    s_idx[p] = id;
  }
  __syncthreads();
  if (p < P_){
    const int myid = s_idx[p];
    bool dup = false;
    for (int q = 0; q < p; ++q) dup |= (s_idx[q] == myid);
    const float pf = (float)myid;
    #pragma unroll
    for (int m = 0; m < M_; ++m){
      const float mean = fminf(fmaxf((float)t + (float)(m-4)*dil, 0.f), (float)(T_-1));
      const float d = (pf - mean) / sigma;
      s_dens[p][m] = dup ? 0.f : expf(-0.5f * d * d);
    }
  }
  __syncthreads();
  if (p < M_){
    float s = 0.f;
    for (int q = 0; q < P_; ++q) s += s_dens[q][p];
    s_col[p] = s;
  }
  __syncthreads();
  if (p < P_){
    float w = 0.f;
    #pragma unroll
    for (int m = 0; m < M_; ++m) w += s_dens[p][m] / s_col[m] * mvals[m];
    idx_out[bt*P_ + p] = s_idx[p];
    w_out[bt*P_ + p]   = w;
  }
}

// ---------------- kernel 2: QKV projection GEMM ----------------
// C(4096x1024) = x(4096x128) @ W(128x1024), scattered to (b,h,t,e), scale for Q/K.
__global__ __launch_bounds__(256) void qkv_kernel(const float* __restrict__ x,
    const float* __restrict__ Wq, const float* __restrict__ Wk, const float* __restrict__ Wv,
    float* __restrict__ Q, float* __restrict__ K, float* __restrict__ V){
  const int tid = threadIdx.x;
  const int tx = tid & 15, ty = tid >> 4;
  const int rowBase = blockIdx.y * 64;
  const int colBase = blockIdx.x * 64;
  const int z = blockIdx.z;
  const float* __restrict__ W = (z==0) ? Wq : (z==1) ? Wk : Wv;
  float* __restrict__ Out     = (z==0) ? Q  : (z==1) ? K  : V;
  const float sc = (z < 2) ? 0.29730177875068026f : 1.0f; // 128^-0.25

  __shared__ float As[64][68];
  __shared__ float Bs[64][68];
  float acc[4][4] = {};

  for (int kk = 0; kk < 128; kk += 64){
    {
      const int k4 = tid & 15, r0 = tid >> 4;
      #pragma unroll
      for (int i = 0; i < 4; ++i){
        const int r = r0 + 16*i;
        float4 v = *(const float4*)(x + (size_t)(rowBase+r)*EMB_ + kk + k4*4);
        *(float4*)(&As[r][k4*4]) = v;
      }
    }
    {
      const int c4 = tid & 15, k0 = tid >> 4;
      #pragma unroll
      for (int i = 0; i < 4; ++i){
        const int k = k0 + 16*i;
        float4 v = *(const float4*)(W + (size_t)(kk+k)*1024 + colBase + c4*4);
        *(float4*)(&Bs[k][c4*4]) = v;
      }
    }
    __syncthreads();
    #pragma unroll 8
    for (int k = 0; k < 64; ++k){
      float a[4], bb[4];
      #pragma unroll
      for (int i = 0; i < 4; ++i) a[i]  = As[ty*4+i][k];
      #pragma unroll
      for (int j = 0; j < 4; ++j) bb[j] = Bs[k][tx*4+j];
      #pragma unroll
      for (int i = 0; i < 4; ++i)
        #pragma unroll
        for (int j = 0; j < 4; ++j) acc[i][j] += a[i]*bb[j];
    }
    __syncthreads();
  }

  const int h  = colBase >> 7;
  const int e0 = (colBase & 127) + tx*4;
  #pragma unroll
  for (int i = 0; i < 4; ++i){
    const int r = rowBase + ty*4 + i;
    const int b = r >> 11, t = r & (T_-1);
    float4 v = { acc[i][0]*sc, acc[i][1]*sc, acc[i][2]*sc, acc[i][3]*sc };
    *(float4*)(Out + ((size_t)((b*NH_+h)*T_) + t)*EMB_ + e0) = v;
  }
}

// ---------------- kernel 3: gather-attention ----------------
__global__ __launch_bounds__(256) void attn_kernel(const float* __restrict__ Q,
    const float* __restrict__ K, const float* __restrict__ V,
    const int* __restrict__ idx, const float* __restrict__ wts,
    float* __restrict__ out){
  const int bt   = blockIdx.x;
  const int b    = bt >> 11, t = bt & (T_-1);
  const int w    = threadIdx.x >> 6, lane = threadIdx.x & 63;
  const int h    = blockIdx.y*4 + w;

  __shared__ int   s_idx[P_];
  __shared__ float s_w[P_];
  if (threadIdx.x < P_){
    s_idx[threadIdx.x] = idx[bt*P_ + threadIdx.x];
    s_w[threadIdx.x]   = wts[bt*P_ + threadIdx.x];
  }
  __syncthreads();

  const size_t headBase = (size_t)(b*NH_ + h) * T_ * EMB_;
  const float2 q = *(const float2*)(Q + headBase + (size_t)t*EMB_ + lane*2);

  const int   myidx = s_idx[lane < P_ ? lane : 0];
  const float myw   = s_w[lane < P_ ? lane : 0];

  const float* __restrict__ Kb = K + headBase;
  float mylogit = 0.f;
  for (int p = 0; p < P_; ++p){
    const int ip = __shfl(myidx, p);
    const float2 kv = *(const float2*)(Kb + (size_t)ip*EMB_ + lane*2);
    float d = q.x*kv.x + q.y*kv.y;
    #pragma unroll
    for (int off = 32; off; off >>= 1) d += __shfl_xor(d, off);
    if (lane == p) mylogit = myw * d;
  }

  float val = (lane < P_) ? mylogit : -INFINITY;
  float mx = val;
  #pragma unroll
  for (int off = 32; off; off >>= 1) mx = fmaxf(mx, __shfl_xor(mx, off));
  float e = (lane < P_) ? expf(val - mx) : 0.f;
  float s = e;
  #pragma unroll
  for (int off = 32; off; off >>= 1) s += __shfl_xor(s, off);
  const float myattn = e / s;

  const float* __restrict__ Vb = V + headBase;
  float2 acc = {0.f, 0.f};
  for (int p = 0; p < P_; ++p){
    const float a  = __shfl(myattn, p);
    const int   ip = __shfl(myidx, p);
    const float2 vv = *(const float2*)(Vb + (size_t)ip*EMB_ + lane*2);
    acc.x += a*vv.x; acc.y += a*vv.y;
  }
  *(float2*)(out + (size_t)bt*(NH_*EMB_) + h*EMB_ + lane*2) = acc;
}

// ---------------- kernel 4: output GEMM + bias ----------------
__global__ __launch_bounds__(256) void out_kernel(const float* __restrict__ A,
    const float* __restrict__ Wu, const float* __restrict__ bu, float* __restrict__ out){
  const int tid = threadIdx.x;
  const int tx = tid & 31, ty = tid >> 5;
  const int rowBase = blockIdx.x * 32;
  __shared__ float As[32][36];
  __shared__ float Bs[32][128];
  float acc[4][4] = {};

  for (int kk = 0; kk < 1024; kk += 32){
    {
      const int r = tid >> 3, k4 = tid & 7;
      float4 v = *(const float4*)(A + (size_t)(rowBase+r)*1024 + kk + k4*4);
      *(float4*)(&As[r][k4*4]) = v;
    }
    {
      const int c4 = tid & 31, k0 = tid >> 5;
      #pragma unroll
      for (int i = 0; i < 4; ++i){
        const int k = k0 + 8*i;
        float4 v = *(const float4*)(Wu + (size_t)(kk+k)*128 + c4*4);
        *(float4*)(&Bs[k][c4*4]) = v;
      }
    }
    __syncthreads();
    #pragma unroll 8
    for (int k = 0; k < 32; ++k){
      float a[4], bb[4];
      #pragma unroll
      for (int i = 0; i < 4; ++i) a[i]  = As[ty*4+i][k];
      #pragma unroll
      for (int j = 0; j < 4; ++j) bb[j] = Bs[k][tx*4+j];
      #pragma unroll
      for (int i = 0; i < 4; ++i)
        #pragma unroll
        for (int j = 0; j < 4; ++j) acc[i][j] += a[i]*bb[j];
    }
    __syncthreads();
  }

  #pragma unroll
  for (int i = 0; i < 4; ++i){
    const int r = rowBase + ty*4 + i;
    const int c0 = tx*4;
    float4 bias = *(const float4*)(bu + c0);
    float4 v = { acc[i][0]+bias.x, acc[i][1]+bias.y, acc[i][2]+bias.z, acc[i][3]+bias.w };
    *(float4*)(out + (size_t)r*EMB_ + c0) = v;
  }
}

// ---------------- launch ----------------
extern "C" void kernel_launch(void* const* d_in, const int* in_sizes, int n_in,
                              void* d_out, int out_size, void* d_ws, size_t ws_size,
                              hipStream_t stream){
  (void)in_sizes; (void)n_in; (void)out_size; (void)ws_size;
  const float* x    = (const float*)d_in[0];
  const float* sp   = (const float*)d_in[1];
  const float* mvl  = (const float*)d_in[2];
  const float* Wq   = (const float*)d_in[3];
  const float* Wk   = (const float*)d_in[4];
  const float* Wv   = (const float*)d_in[5];
  const float* Wu   = (const float*)d_in[6];
  const float* bu   = (const float*)d_in[7];
  float* out = (float*)d_out;

  const size_t n = (size_t)B_*NH_*T_*EMB_;           // 4,194,304
  float* Q    = (float*)d_ws;
  float* K    = Q + n;
  float* V    = K + n;
  float* attn = V + n;                               // (b,t,h*e) layout
  int*   idxb = (int*)(attn + n);
  float* wb   = (float*)(idxb + (size_t)B_*T_*P_);

  idx_weights_kernel<<<B_*T_, 64, 0, stream>>>(sp, mvl, idxb, wb);
  qkv_kernel<<<dim3(16, 64, 3), 256, 0, stream>>>(x, Wq, Wk, Wv, Q, K, V);
  attn_kernel<<<dim3(B_*T_, 2), 256, 0, stream>>>(Q, K, V, idxb, wb, attn);
  out_kernel<<<(B_*T_)/32, 256, 0, stream>>>(attn, Wu, bu, out);
}

// Round 4
// 242.034 us; speedup vs baseline: 1.0021x; 1.0021x over previous
//
#include <hip/hip_runtime.h>
#include <math.h>

#define B_    2
#define T_    2048
#define EMB_  128
#define NH_   8
#define M_    9
#define P_    36
#define GADD_ 2

// ---------------- Threefry-2x32 (jax PRNG) ----------------
__device__ __forceinline__ unsigned rotl32(unsigned x, int r){ return (x<<r)|(x>>(32-r)); }

struct U2 { unsigned x, y; };

__device__ __forceinline__ U2 tf2x32(U2 key, U2 ctr){
  unsigned ks[3] = { key.x, key.y, key.x ^ key.y ^ 0x1BD11BDAu };
  unsigned x0 = ctr.x + ks[0], x1 = ctr.y + ks[1];
  const int rotA[4] = {13,15,26,6}, rotB[4] = {17,29,16,24};
  #pragma unroll
  for (int r = 0; r < 5; ++r){
    const int* rr = (r & 1) ? rotB : rotA;
    #pragma unroll
    for (int i = 0; i < 4; ++i){ x0 += x1; x1 = rotl32(x1, rr[i]); x1 ^= x0; }
    x0 += ks[(r+1)%3];
    x1 += ks[(r+2)%3] + (unsigned)(r+1);
  }
  return { x0, x1 };
}

// randint(key(42),(B,T,M,GADD),0,T), partitionable threefry path:
//   k2 = tf2x32((0,42),(0,1));  bits(f) = xor(tf2x32(k2,(0,f)));  idx = bits & 2047
__device__ unsigned glob_rand(unsigned f){
  U2 k2 = tf2x32({0u, 42u}, {0u, 1u});
  U2 o  = tf2x32(k2, {0u, f});
  return (o.x ^ o.y) & (unsigned)(T_-1);
}

// round-to-nearest-even f32 -> bf16 pair packed as uint (lo = a, hi = b)
__device__ __forceinline__ unsigned pack_bf16x2(float a, float b){
  unsigned ua = __float_as_uint(a), ub = __float_as_uint(b);
  ua = ua + 0x7fffu + ((ua >> 16) & 1u);
  ub = ub + 0x7fffu + ((ub >> 16) & 1u);
  return (ua >> 16) | (ub & 0xffff0000u);
}

// ---------------- kernel 1: indices + weights ----------------
__global__ void idx_weights_kernel(const float* __restrict__ sp, const float* __restrict__ mvals,
                                   int* __restrict__ idx_out, float* __restrict__ w_out){
  const int bt = blockIdx.x;
  const int t  = bt & (T_-1);
  const int p  = threadIdx.x;
  __shared__ int   s_idx[P_];
  __shared__ float s_dens[P_][M_];
  __shared__ float s_col[M_];

  const float dil  = sp[0];
  const float xs   = sp[1] + 2.0f;                    // sigma_raw + SIGMA_BOOST
  const float sigma = xs + log1pf(expf(-xs)) + 1e-7f; // softplus + EPS

  if (p < P_){
    const int m = p >> 2, j = p & 3;
    const float mean = fminf(fmaxf((float)t + (float)(m-4)*dil, 0.f), (float)(T_-1));
    int id;
    if      (j == 0) id = (int)floorf(mean);
    else if (j == 1) id = min((int)floorf(mean) + 1, T_-1);
    else {
      const unsigned f = ((unsigned)bt * M_ + (unsigned)m) * GADD_ + (unsigned)(j-2);
      id = (int)glob_rand(f);
    }
    s_idx[p] = id;
  }
  __syncthreads();
  if (p < P_){
    const int myid = s_idx[p];
    bool dup = false;
    for (int q = 0; q < p; ++q) dup |= (s_idx[q] == myid);
    const float pf = (float)myid;
    #pragma unroll
    for (int m = 0; m < M_; ++m){
      const float mean = fminf(fmaxf((float)t + (float)(m-4)*dil, 0.f), (float)(T_-1));
      const float d = (pf - mean) / sigma;
      s_dens[p][m] = dup ? 0.f : expf(-0.5f * d * d);
    }
  }
  __syncthreads();
  if (p < M_){
    float s = 0.f;
    for (int q = 0; q < P_; ++q) s += s_dens[q][p];
    s_col[p] = s;
  }
  __syncthreads();
  if (p < P_){
    float w = 0.f;
    #pragma unroll
    for (int m = 0; m < M_; ++m) w += s_dens[p][m] / s_col[m] * mvals[m];
    idx_out[bt*P_ + p] = s_idx[p];
    w_out[bt*P_ + p]   = w;
  }
}

// ---------------- kernel 2: QKV projection GEMM ----------------
// C(4096x1024) = x(4096x128) @ W(128x1024), layout (b,t,h,e).
// Q stays f32 (scaled); K (scaled) and V stored bf16.
__global__ __launch_bounds__(256) void qkv_kernel(const float* __restrict__ x,
    const float* __restrict__ Wq, const float* __restrict__ Wk, const float* __restrict__ Wv,
    float* __restrict__ Q, unsigned short* __restrict__ Kh, unsigned short* __restrict__ Vh){
  const int tid = threadIdx.x;
  const int tx = tid & 15, ty = tid >> 4;
  const int rowBase = blockIdx.y * 64;
  const int colBase = blockIdx.x * 64;
  const int z = blockIdx.z;
  const float* __restrict__ W = (z==0) ? Wq : (z==1) ? Wk : Wv;
  const float sc = (z < 2) ? 0.29730177875068026f : 1.0f; // 128^-0.25

  __shared__ float As[64][68];
  __shared__ float Bs[64][68];
  float acc[4][4] = {};

  for (int kk = 0; kk < 128; kk += 64){
    {
      const int k4 = tid & 15, r0 = tid >> 4;
      #pragma unroll
      for (int i = 0; i < 4; ++i){
        const int r = r0 + 16*i;
        float4 v = *(const float4*)(x + (size_t)(rowBase+r)*EMB_ + kk + k4*4);
        *(float4*)(&As[r][k4*4]) = v;
      }
    }
    {
      const int c4 = tid & 15, k0 = tid >> 4;
      #pragma unroll
      for (int i = 0; i < 4; ++i){
        const int k = k0 + 16*i;
        float4 v = *(const float4*)(W + (size_t)(kk+k)*1024 + colBase + c4*4);
        *(float4*)(&Bs[k][c4*4]) = v;
      }
    }
    __syncthreads();
    #pragma unroll 8
    for (int k = 0; k < 64; ++k){
      float a[4], bb[4];
      #pragma unroll
      for (int i = 0; i < 4; ++i) a[i]  = As[ty*4+i][k];
      #pragma unroll
      for (int j = 0; j < 4; ++j) bb[j] = Bs[k][tx*4+j];
      #pragma unroll
      for (int i = 0; i < 4; ++i)
        #pragma unroll
        for (int j = 0; j < 4; ++j) acc[i][j] += a[i]*bb[j];
    }
    __syncthreads();
  }

  #pragma unroll
  for (int i = 0; i < 4; ++i){
    const int r = rowBase + ty*4 + i;            // r = b*T + t
    const size_t off = (size_t)r*1024 + colBase + tx*4;  // (b,t, h*128+e)
    if (z == 0){
      float4 v = { acc[i][0]*sc, acc[i][1]*sc, acc[i][2]*sc, acc[i][3]*sc };
      *(float4*)(Q + off) = v;
    } else {
      unsigned short* __restrict__ Outh = (z==1) ? Kh : Vh;
      uint2 pv = { pack_bf16x2(acc[i][0]*sc, acc[i][1]*sc),
                   pack_bf16x2(acc[i][2]*sc, acc[i][3]*sc) };
      *(uint2*)(Outh + off) = pv;
    }
  }
}

// ---------------- kernel 3: gather-attention ----------------
// One block per (b,t); 8 waves = 8 heads. K/V in bf16, layout (b,t,h,e).
__global__ __launch_bounds__(512) void attn_kernel(const float* __restrict__ Q,
    const unsigned short* __restrict__ K, const unsigned short* __restrict__ V,
    const int* __restrict__ idx, const float* __restrict__ wts,
    float* __restrict__ out){
  const int bid = blockIdx.x;
  const int bt  = ((bid & 7) << 9) | (bid >> 3);   // XCD swizzle, bijective (4096 % 8 == 0)
  const int b   = bt >> 11;
  const int h    = threadIdx.x >> 6, lane = threadIdx.x & 63;

  __shared__ int   s_idx[P_];
  __shared__ float s_w[P_];
  if (threadIdx.x < P_){
    s_idx[threadIdx.x] = idx[bt*P_ + threadIdx.x];
    s_w[threadIdx.x]   = wts[bt*P_ + threadIdx.x];
  }
  __syncthreads();

  const size_t rowOff = (size_t)bt*1024 + h*EMB_ + lane*2;
  const float2 q = *(const float2*)(Q + rowOff);
  const size_t bBase = (size_t)b * T_ * 1024 + h*EMB_ + lane*2;

  const int   myidx = s_idx[lane < P_ ? lane : 0];
  const float myw   = s_w[lane < P_ ? lane : 0];

  float mylogit = 0.f;
  for (int p = 0; p < P_; ++p){
    const int ip = __shfl(myidx, p);
    const unsigned u = *(const unsigned*)(K + bBase + (size_t)ip*1024);
    const float kx = __uint_as_float(u << 16);
    const float ky = __uint_as_float(u & 0xffff0000u);
    float d = q.x*kx + q.y*ky;
    #pragma unroll
    for (int off = 32; off; off >>= 1) d += __shfl_xor(d, off);
    if (lane == p) mylogit = myw * d;
  }

  float val = (lane < P_) ? mylogit : -INFINITY;
  float mx = val;
  #pragma unroll
  for (int off = 32; off; off >>= 1) mx = fmaxf(mx, __shfl_xor(mx, off));
  float e = (lane < P_) ? expf(val - mx) : 0.f;
  float s = e;
  #pragma unroll
  for (int off = 32; off; off >>= 1) s += __shfl_xor(s, off);
  const float myattn = e / s;

  float2 acc = {0.f, 0.f};
  for (int p = 0; p < P_; ++p){
    const float a  = __shfl(myattn, p);
    const int   ip = __shfl(myidx, p);
    const unsigned u = *(const unsigned*)(V + bBase + (size_t)ip*1024);
    acc.x += a * __uint_as_float(u << 16);
    acc.y += a * __uint_as_float(u & 0xffff0000u);
  }
  *(float2*)(out + rowOff) = acc;
}

// ---------------- kernel 4: output GEMM + bias ----------------
__global__ __launch_bounds__(256) void out_kernel(const float* __restrict__ A,
    const float* __restrict__ Wu, const float* __restrict__ bu, float* __restrict__ out){
  const int tid = threadIdx.x;
  const int tx = tid & 31, ty = tid >> 5;
  const int rowBase = blockIdx.x * 32;
  __shared__ float As[32][36];
  __shared__ float Bs[32][128];
  float acc[4][4] = {};

  for (int kk = 0; kk < 1024; kk += 32){
    {
      const int r = tid >> 3, k4 = tid & 7;
      float4 v = *(const float4*)(A + (size_t)(rowBase+r)*1024 + kk + k4*4);
      *(float4*)(&As[r][k4*4]) = v;
    }
    {
      const int c4 = tid & 31, k0 = tid >> 5;
      #pragma unroll
      for (int i = 0; i < 4; ++i){
        const int k = k0 + 8*i;
        float4 v = *(const float4*)(Wu + (size_t)(kk+k)*128 + c4*4);
        *(float4*)(&Bs[k][c4*4]) = v;
      }
    }
    __syncthreads();
    #pragma unroll 8
    for (int k = 0; k < 32; ++k){
      float a[4], bb[4];
      #pragma unroll
      for (int i = 0; i < 4; ++i) a[i]  = As[ty*4+i][k];
      #pragma unroll
      for (int j = 0; j < 4; ++j) bb[j] = Bs[k][tx*4+j];
      #pragma unroll
      for (int i = 0; i < 4; ++i)
        #pragma unroll
        for (int j = 0; j < 4; ++j) acc[i][j] += a[i]*bb[j];
    }
    __syncthreads();
  }

  #pragma unroll
  for (int i = 0; i < 4; ++i){
    const int r = rowBase + ty*4 + i;
    const int c0 = tx*4;
    float4 bias = *(const float4*)(bu + c0);
    float4 v = { acc[i][0]+bias.x, acc[i][1]+bias.y, acc[i][2]+bias.z, acc[i][3]+bias.w };
    *(float4*)(out + (size_t)r*EMB_ + c0) = v;
  }
}

// ---------------- launch ----------------
extern "C" void kernel_launch(void* const* d_in, const int* in_sizes, int n_in,
                              void* d_out, int out_size, void* d_ws, size_t ws_size,
                              hipStream_t stream){
  (void)in_sizes; (void)n_in; (void)out_size; (void)ws_size;
  const float* x    = (const float*)d_in[0];
  const float* sp   = (const float*)d_in[1];
  const float* mvl  = (const float*)d_in[2];
  const float* Wq   = (const float*)d_in[3];
  const float* Wk   = (const float*)d_in[4];
  const float* Wv   = (const float*)d_in[5];
  const float* Wu   = (const float*)d_in[6];
  const float* bu   = (const float*)d_in[7];
  float* out = (float*)d_out;

  const size_t n = (size_t)B_*NH_*T_*EMB_;           // 4,194,304
  float*          Q    = (float*)d_ws;               // n f32
  unsigned short* Kh   = (unsigned short*)(Q + n);   // n bf16
  unsigned short* Vh   = Kh + n;                     // n bf16
  float*          attn = (float*)(Vh + n);           // n f32, (b,t,h*e)
  int*            idxb = (int*)(attn + n);
  float*          wb   = (float*)(idxb + (size_t)B_*T_*P_);

  idx_weights_kernel<<<B_*T_, 64, 0, stream>>>(sp, mvl, idxb, wb);
  qkv_kernel<<<dim3(16, 64, 3), 256, 0, stream>>>(x, Wq, Wk, Wv, Q, Kh, Vh);
  attn_kernel<<<B_*T_, 512, 0, stream>>>(Q, Kh, Vh, idxb, wb, attn);
  out_kernel<<<(B_*T_)/32, 256, 0, stream>>>(attn, Wu, bu, out);
}

// Round 5
// 175.234 us; speedup vs baseline: 1.3841x; 1.3812x over previous
//
#include <hip/hip_runtime.h>
#include <math.h>

#define B_    2
#define T_    2048
#define EMB_  128
#define NH_   8
#define M_    9
#define P_    36
#define GADD_ 2

// ---------------- Threefry-2x32 (jax PRNG) ----------------
__device__ __forceinline__ unsigned rotl32(unsigned x, int r){ return (x<<r)|(x>>(32-r)); }

struct U2 { unsigned x, y; };

__device__ __forceinline__ U2 tf2x32(U2 key, U2 ctr){
  unsigned ks[3] = { key.x, key.y, key.x ^ key.y ^ 0x1BD11BDAu };
  unsigned x0 = ctr.x + ks[0], x1 = ctr.y + ks[1];
  const int rotA[4] = {13,15,26,6}, rotB[4] = {17,29,16,24};
  #pragma unroll
  for (int r = 0; r < 5; ++r){
    const int* rr = (r & 1) ? rotB : rotA;
    #pragma unroll
    for (int i = 0; i < 4; ++i){ x0 += x1; x1 = rotl32(x1, rr[i]); x1 ^= x0; }
    x0 += ks[(r+1)%3];
    x1 += ks[(r+2)%3] + (unsigned)(r+1);
  }
  return { x0, x1 };
}

// randint(key(42),(B,T,M,GADD),0,T), partitionable threefry path:
//   k2 = tf2x32((0,42),(0,1));  bits(f) = xor(tf2x32(k2,(0,f)));  idx = bits & 2047
__device__ unsigned glob_rand(unsigned f){
  U2 k2 = tf2x32({0u, 42u}, {0u, 1u});
  U2 o  = tf2x32(k2, {0u, f});
  return (o.x ^ o.y) & (unsigned)(T_-1);
}

// round-to-nearest-even f32 -> bf16 pair packed as uint (lo = a, hi = b)
__device__ __forceinline__ unsigned pack_bf16x2(float a, float b){
  unsigned ua = __float_as_uint(a), ub = __float_as_uint(b);
  ua = ua + 0x7fffu + ((ua >> 16) & 1u);
  ub = ub + 0x7fffu + ((ub >> 16) & 1u);
  return (ua >> 16) | (ub & 0xffff0000u);
}

// ---------------- kernel 1: indices + weights ----------------
__global__ void idx_weights_kernel(const float* __restrict__ sp, const float* __restrict__ mvals,
                                   int* __restrict__ idx_out, float* __restrict__ w_out){
  const int bt = blockIdx.x;
  const int t  = bt & (T_-1);
  const int p  = threadIdx.x;
  __shared__ int   s_idx[P_];
  __shared__ float s_dens[P_][M_];
  __shared__ float s_col[M_];

  const float dil  = sp[0];
  const float xs   = sp[1] + 2.0f;                    // sigma_raw + SIGMA_BOOST
  const float sigma = xs + log1pf(expf(-xs)) + 1e-7f; // softplus + EPS

  if (p < P_){
    const int m = p >> 2, j = p & 3;
    const float mean = fminf(fmaxf((float)t + (float)(m-4)*dil, 0.f), (float)(T_-1));
    int id;
    if      (j == 0) id = (int)floorf(mean);
    else if (j == 1) id = min((int)floorf(mean) + 1, T_-1);
    else {
      const unsigned f = ((unsigned)bt * M_ + (unsigned)m) * GADD_ + (unsigned)(j-2);
      id = (int)glob_rand(f);
    }
    s_idx[p] = id;
  }
  __syncthreads();
  if (p < P_){
    const int myid = s_idx[p];
    bool dup = false;
    for (int q = 0; q < p; ++q) dup |= (s_idx[q] == myid);
    const float pf = (float)myid;
    #pragma unroll
    for (int m = 0; m < M_; ++m){
      const float mean = fminf(fmaxf((float)t + (float)(m-4)*dil, 0.f), (float)(T_-1));
      const float d = (pf - mean) / sigma;
      s_dens[p][m] = dup ? 0.f : expf(-0.5f * d * d);
    }
  }
  __syncthreads();
  if (p < M_){
    float s = 0.f;
    for (int q = 0; q < P_; ++q) s += s_dens[q][p];
    s_col[p] = s;
  }
  __syncthreads();
  if (p < P_){
    float w = 0.f;
    #pragma unroll
    for (int m = 0; m < M_; ++m) w += s_dens[p][m] / s_col[m] * mvals[m];
    idx_out[bt*P_ + p] = s_idx[p];
    w_out[bt*P_ + p]   = w;
  }
}

// ---------------- kernel 2: QKV projection GEMM ----------------
// C(4096x1024) = x(4096x128) @ W(128x1024), layout (b,t,h,e).
// Q stays f32 (scaled); K (scaled) and V stored bf16.
__global__ __launch_bounds__(256) void qkv_kernel(const float* __restrict__ x,
    const float* __restrict__ Wq, const float* __restrict__ Wk, const float* __restrict__ Wv,
    float* __restrict__ Q, unsigned short* __restrict__ Kh, unsigned short* __restrict__ Vh){
  const int tid = threadIdx.x;
  const int tx = tid & 15, ty = tid >> 4;
  const int rowBase = blockIdx.y * 64;
  const int colBase = blockIdx.x * 64;
  const int z = blockIdx.z;
  const float* __restrict__ W = (z==0) ? Wq : (z==1) ? Wk : Wv;
  const float sc = (z < 2) ? 0.29730177875068026f : 1.0f; // 128^-0.25

  __shared__ float As[64][68];
  __shared__ float Bs[64][68];
  float acc[4][4] = {};

  for (int kk = 0; kk < 128; kk += 64){
    {
      const int k4 = tid & 15, r0 = tid >> 4;
      #pragma unroll
      for (int i = 0; i < 4; ++i){
        const int r = r0 + 16*i;
        float4 v = *(const float4*)(x + (size_t)(rowBase+r)*EMB_ + kk + k4*4);
        *(float4*)(&As[r][k4*4]) = v;
      }
    }
    {
      const int c4 = tid & 15, k0 = tid >> 4;
      #pragma unroll
      for (int i = 0; i < 4; ++i){
        const int k = k0 + 16*i;
        float4 v = *(const float4*)(W + (size_t)(kk+k)*1024 + colBase + c4*4);
        *(float4*)(&Bs[k][c4*4]) = v;
      }
    }
    __syncthreads();
    #pragma unroll 8
    for (int k = 0; k < 64; ++k){
      float a[4], bb[4];
      #pragma unroll
      for (int i = 0; i < 4; ++i) a[i]  = As[ty*4+i][k];
      #pragma unroll
      for (int j = 0; j < 4; ++j) bb[j] = Bs[k][tx*4+j];
      #pragma unroll
      for (int i = 0; i < 4; ++i)
        #pragma unroll
        for (int j = 0; j < 4; ++j) acc[i][j] += a[i]*bb[j];
    }
    __syncthreads();
  }

  #pragma unroll
  for (int i = 0; i < 4; ++i){
    const int r = rowBase + ty*4 + i;            // r = b*T + t
    const size_t off = (size_t)r*1024 + colBase + tx*4;  // (b,t, h*128+e)
    if (z == 0){
      float4 v = { acc[i][0]*sc, acc[i][1]*sc, acc[i][2]*sc, acc[i][3]*sc };
      *(float4*)(Q + off) = v;
    } else {
      unsigned short* __restrict__ Outh = (z==1) ? Kh : Vh;
      uint2 pv = { pack_bf16x2(acc[i][0]*sc, acc[i][1]*sc),
                   pack_bf16x2(acc[i][2]*sc, acc[i][3]*sc) };
      *(uint2*)(Outh + off) = pv;
    }
  }
}

// ---------------- kernel 3: gather-attention (batched reduce) ----------------
// One block per (b,t); 8 waves = 8 heads. K/V bf16, layout (b,t,h,e).
#define RSTR 38   // red row stride (f32): (38*r+p)%32 -> 2-way max, free
__global__ __launch_bounds__(512) void attn_kernel(const float* __restrict__ Q,
    const unsigned short* __restrict__ K, const unsigned short* __restrict__ V,
    const int* __restrict__ idx, const float* __restrict__ wts,
    float* __restrict__ out){
  const int bid = blockIdx.x;
  const int bt  = ((bid & 7) << 9) | (bid >> 3);   // XCD swizzle, bijective
  const int b   = bt >> 11;
  const int h   = threadIdx.x >> 6, lane = threadIdx.x & 63;

  __shared__ int   s_koff[P_];
  __shared__ float s_w[P_];
  __shared__ float s_red[NH_ * 32 * RSTR];
  __shared__ float s_a[NH_][40];

  if (threadIdx.x < P_){
    s_koff[threadIdx.x] = idx[bt*P_ + threadIdx.x] << 10;   // element offset ip*1024
    s_w[threadIdx.x]    = wts[bt*P_ + threadIdx.x];
  }
  __syncthreads();

  const size_t rowOff = (size_t)bt*1024 + h*EMB_ + lane*2;
  const float2 q = *(const float2*)(Q + rowOff);
  const unsigned short* __restrict__ Kb = K + (size_t)b*T_*1024 + h*EMB_ + lane*2;
  const unsigned short* __restrict__ Vb = V + (size_t)b*T_*1024 + h*EMB_ + lane*2;

  // ---- Phase A: per-lane partial dots for all 36 points (independent loads) ----
  float pr[P_];
  #pragma unroll
  for (int c = 0; c < 4; ++c){
    unsigned u[9]; int ko[9];
    #pragma unroll
    for (int j = 0; j < 9; ++j) ko[j] = s_koff[c*9+j];
    #pragma unroll
    for (int j = 0; j < 9; ++j) u[j] = *(const unsigned*)(Kb + ko[j]);
    #pragma unroll
    for (int j = 0; j < 9; ++j){
      const float kx = __uint_as_float(u[j] << 16);
      const float ky = __uint_as_float(u[j] & 0xffff0000u);
      pr[c*9+j] = q.x*kx + q.y*ky;
    }
  }

  // ---- Phase B: fold 64->32 lanes, LDS transpose, column sum ----
  #pragma unroll
  for (int p = 0; p < P_; ++p) pr[p] += __shfl_xor(pr[p], 32);

  float* __restrict__ myred = &s_red[h * 32 * RSTR];
  if (lane < 32){
    float* dst = myred + lane * RSTR;
    #pragma unroll
    for (int i = 0; i < 18; ++i){
      float2 v2 = { pr[2*i], pr[2*i+1] };
      *(float2*)(dst + 2*i) = v2;
    }
  }
  const int pcol = (lane < P_) ? lane : 0;
  float s0=0.f, s1=0.f, s2=0.f, s3=0.f;
  #pragma unroll
  for (int r = 0; r < 32; r += 4){
    s0 += myred[(r+0)*RSTR + pcol];
    s1 += myred[(r+1)*RSTR + pcol];
    s2 += myred[(r+2)*RSTR + pcol];
    s3 += myred[(r+3)*RSTR + pcol];
  }
  const float logit = (s0+s1)+(s2+s3);

  // ---- softmax over points (lane-per-point) ----
  float val = (lane < P_) ? logit * s_w[pcol] : -INFINITY;
  float mx = val;
  #pragma unroll
  for (int off = 32; off; off >>= 1) mx = fmaxf(mx, __shfl_xor(mx, off));
  float e = (lane < P_) ? expf(val - mx) : 0.f;
  float s = e;
  #pragma unroll
  for (int off = 32; off; off >>= 1) s += __shfl_xor(s, off);
  if (lane < P_) s_a[h][lane] = e / s;

  // ---- Phase C: PV gather with broadcast weights ----
  float2 acc = {0.f, 0.f};
  #pragma unroll
  for (int c = 0; c < 9; ++c){
    const float4 av = *(const float4*)(&s_a[h][4*c]);
    unsigned u[4]; int ko[4];
    #pragma unroll
    for (int j = 0; j < 4; ++j) ko[j] = s_koff[c*4+j];
    #pragma unroll
    for (int j = 0; j < 4; ++j) u[j] = *(const unsigned*)(Vb + ko[j]);
    const float a0 = av.x, a1 = av.y, a2 = av.z, a3 = av.w;
    acc.x += a0*__uint_as_float(u[0] << 16); acc.y += a0*__uint_as_float(u[0] & 0xffff0000u);
    acc.x += a1*__uint_as_float(u[1] << 16); acc.y += a1*__uint_as_float(u[1] & 0xffff0000u);
    acc.x += a2*__uint_as_float(u[2] << 16); acc.y += a2*__uint_as_float(u[2] & 0xffff0000u);
    acc.x += a3*__uint_as_float(u[3] << 16); acc.y += a3*__uint_as_float(u[3] & 0xffff0000u);
  }
  *(float2*)(out + rowOff) = acc;
}

// ---------------- kernel 4: output GEMM + bias ----------------
__global__ __launch_bounds__(256) void out_kernel(const float* __restrict__ A,
    const float* __restrict__ Wu, const float* __restrict__ bu, float* __restrict__ out){
  const int tid = threadIdx.x;
  const int tx = tid & 31, ty = tid >> 5;
  const int rowBase = blockIdx.x * 32;
  __shared__ float As[32][36];
  __shared__ float Bs[32][128];
  float acc[4][4] = {};

  for (int kk = 0; kk < 1024; kk += 32){
    {
      const int r = tid >> 3, k4 = tid & 7;
      float4 v = *(const float4*)(A + (size_t)(rowBase+r)*1024 + kk + k4*4);
      *(float4*)(&As[r][k4*4]) = v;
    }
    {
      const int c4 = tid & 31, k0 = tid >> 5;
      #pragma unroll
      for (int i = 0; i < 4; ++i){
        const int k = k0 + 8*i;
        float4 v = *(const float4*)(Wu + (size_t)(kk+k)*128 + c4*4);
        *(float4*)(&Bs[k][c4*4]) = v;
      }
    }
    __syncthreads();
    #pragma unroll 8
    for (int k = 0; k < 32; ++k){
      float a[4], bb[4];
      #pragma unroll
      for (int i = 0; i < 4; ++i) a[i]  = As[ty*4+i][k];
      #pragma unroll
      for (int j = 0; j < 4; ++j) bb[j] = Bs[k][tx*4+j];
      #pragma unroll
      for (int i = 0; i < 4; ++i)
        #pragma unroll
        for (int j = 0; j < 4; ++j) acc[i][j] += a[i]*bb[j];
    }
    __syncthreads();
  }

  #pragma unroll
  for (int i = 0; i < 4; ++i){
    const int r = rowBase + ty*4 + i;
    const int c0 = tx*4;
    float4 bias = *(const float4*)(bu + c0);
    float4 v = { acc[i][0]+bias.x, acc[i][1]+bias.y, acc[i][2]+bias.z, acc[i][3]+bias.w };
    *(float4*)(out + (size_t)r*EMB_ + c0) = v;
  }
}

// ---------------- launch ----------------
extern "C" void kernel_launch(void* const* d_in, const int* in_sizes, int n_in,
                              void* d_out, int out_size, void* d_ws, size_t ws_size,
                              hipStream_t stream){
  (void)in_sizes; (void)n_in; (void)out_size; (void)ws_size;
  const float* x    = (const float*)d_in[0];
  const float* sp   = (const float*)d_in[1];
  const float* mvl  = (const float*)d_in[2];
  const float* Wq   = (const float*)d_in[3];
  const float* Wk   = (const float*)d_in[4];
  const float* Wv   = (const float*)d_in[5];
  const float* Wu   = (const float*)d_in[6];
  const float* bu   = (const float*)d_in[7];
  float* out = (float*)d_out;

  const size_t n = (size_t)B_*NH_*T_*EMB_;           // 4,194,304
  float*          Q    = (float*)d_ws;               // n f32
  unsigned short* Kh   = (unsigned short*)(Q + n);   // n bf16
  unsigned short* Vh   = Kh + n;                     // n bf16
  float*          attn = (float*)(Vh + n);           // n f32, (b,t,h*e)
  int*            idxb = (int*)(attn + n);
  float*          wb   = (float*)(idxb + (size_t)B_*T_*P_);

  idx_weights_kernel<<<B_*T_, 64, 0, stream>>>(sp, mvl, idxb, wb);
  qkv_kernel<<<dim3(16, 64, 3), 256, 0, stream>>>(x, Wq, Wk, Wv, Q, Kh, Vh);
  attn_kernel<<<B_*T_, 512, 0, stream>>>(Q, Kh, Vh, idxb, wb, attn);
  out_kernel<<<(B_*T_)/32, 256, 0, stream>>>(attn, Wu, bu, out);
}

// Round 6
// 129.679 us; speedup vs baseline: 1.8704x; 1.3513x over previous
//
#include <hip/hip_runtime.h>
#include <math.h>

#define B_    2
#define T_    2048
#define EMB_  128
#define NH_   8
#define M_    9
#define P_    36
#define GADD_ 2

// ---------------- Threefry-2x32 (jax PRNG) ----------------
__device__ __forceinline__ unsigned rotl32(unsigned x, int r){ return (x<<r)|(x>>(32-r)); }

struct U2 { unsigned x, y; };

__device__ __forceinline__ U2 tf2x32(U2 key, U2 ctr){
  unsigned ks[3] = { key.x, key.y, key.x ^ key.y ^ 0x1BD11BDAu };
  unsigned x0 = ctr.x + ks[0], x1 = ctr.y + ks[1];
  const int rotA[4] = {13,15,26,6}, rotB[4] = {17,29,16,24};
  #pragma unroll
  for (int r = 0; r < 5; ++r){
    const int* rr = (r & 1) ? rotB : rotA;
    #pragma unroll
    for (int i = 0; i < 4; ++i){ x0 += x1; x1 = rotl32(x1, rr[i]); x1 ^= x0; }
    x0 += ks[(r+1)%3];
    x1 += ks[(r+2)%3] + (unsigned)(r+1);
  }
  return { x0, x1 };
}

// randint(key(42),(B,T,M,GADD),0,T), partitionable threefry path:
//   k2 = tf2x32((0,42),(0,1));  bits(f) = xor(tf2x32(k2,(0,f)));  idx = bits & 2047
__device__ unsigned glob_rand(unsigned f){
  U2 k2 = tf2x32({0u, 42u}, {0u, 1u});
  U2 o  = tf2x32(k2, {0u, f});
  return (o.x ^ o.y) & (unsigned)(T_-1);
}

// round-to-nearest-even f32 -> bf16 pair packed as uint (lo = a, hi = b)
__device__ __forceinline__ unsigned pack_bf16x2(float a, float b){
  unsigned ua = __float_as_uint(a), ub = __float_as_uint(b);
  ua = ua + 0x7fffu + ((ua >> 16) & 1u);
  ub = ub + 0x7fffu + ((ub >> 16) & 1u);
  return (ua >> 16) | (ub & 0xffff0000u);
}

// ---------------- kernel 1: indices + weights ----------------
__global__ void idx_weights_kernel(const float* __restrict__ sp, const float* __restrict__ mvals,
                                   int* __restrict__ idx_out, float* __restrict__ w_out){
  const int bt = blockIdx.x;
  const int t  = bt & (T_-1);
  const int p  = threadIdx.x;
  __shared__ int   s_idx[P_];
  __shared__ float s_dens[P_][M_];
  __shared__ float s_col[M_];

  const float dil  = sp[0];
  const float xs   = sp[1] + 2.0f;                    // sigma_raw + SIGMA_BOOST
  const float sigma = xs + log1pf(expf(-xs)) + 1e-7f; // softplus + EPS

  if (p < P_){
    const int m = p >> 2, j = p & 3;
    const float mean = fminf(fmaxf((float)t + (float)(m-4)*dil, 0.f), (float)(T_-1));
    int id;
    if      (j == 0) id = (int)floorf(mean);
    else if (j == 1) id = min((int)floorf(mean) + 1, T_-1);
    else {
      const unsigned f = ((unsigned)bt * M_ + (unsigned)m) * GADD_ + (unsigned)(j-2);
      id = (int)glob_rand(f);
    }
    s_idx[p] = id;
  }
  __syncthreads();
  if (p < P_){
    const int myid = s_idx[p];
    bool dup = false;
    for (int q = 0; q < p; ++q) dup |= (s_idx[q] == myid);
    const float pf = (float)myid;
    #pragma unroll
    for (int m = 0; m < M_; ++m){
      const float mean = fminf(fmaxf((float)t + (float)(m-4)*dil, 0.f), (float)(T_-1));
      const float d = (pf - mean) / sigma;
      s_dens[p][m] = dup ? 0.f : expf(-0.5f * d * d);
    }
  }
  __syncthreads();
  if (p < M_){
    float s = 0.f;
    for (int q = 0; q < P_; ++q) s += s_dens[q][p];
    s_col[p] = s;
  }
  __syncthreads();
  if (p < P_){
    float w = 0.f;
    #pragma unroll
    for (int m = 0; m < M_; ++m) w += s_dens[p][m] / s_col[m] * mvals[m];
    idx_out[bt*P_ + p] = s_idx[p];
    w_out[bt*P_ + p]   = w;
  }
}

// ---------------- kernel 2: QKV projection GEMM ----------------
// C(4096x1024) = x(4096x128) @ W(128x1024), layout (b,t,h,e).
// Q stays f32 (scaled); K (scaled) and V stored bf16.
__global__ __launch_bounds__(256) void qkv_kernel(const float* __restrict__ x,
    const float* __restrict__ Wq, const float* __restrict__ Wk, const float* __restrict__ Wv,
    float* __restrict__ Q, unsigned short* __restrict__ Kh, unsigned short* __restrict__ Vh){
  const int tid = threadIdx.x;
  const int tx = tid & 15, ty = tid >> 4;
  const int rowBase = blockIdx.y * 64;
  const int colBase = blockIdx.x * 64;
  const int z = blockIdx.z;
  const float* __restrict__ W = (z==0) ? Wq : (z==1) ? Wk : Wv;
  const float sc = (z < 2) ? 0.29730177875068026f : 1.0f; // 128^-0.25

  __shared__ float As[64][68];
  __shared__ float Bs[64][68];
  float acc[4][4] = {};

  for (int kk = 0; kk < 128; kk += 64){
    {
      const int k4 = tid & 15, r0 = tid >> 4;
      #pragma unroll
      for (int i = 0; i < 4; ++i){
        const int r = r0 + 16*i;
        float4 v = *(const float4*)(x + (size_t)(rowBase+r)*EMB_ + kk + k4*4);
        *(float4*)(&As[r][k4*4]) = v;
      }
    }
    {
      const int c4 = tid & 15, k0 = tid >> 4;
      #pragma unroll
      for (int i = 0; i < 4; ++i){
        const int k = k0 + 16*i;
        float4 v = *(const float4*)(W + (size_t)(kk+k)*1024 + colBase + c4*4);
        *(float4*)(&Bs[k][c4*4]) = v;
      }
    }
    __syncthreads();
    #pragma unroll 8
    for (int k = 0; k < 64; ++k){
      float a[4], bb[4];
      #pragma unroll
      for (int i = 0; i < 4; ++i) a[i]  = As[ty*4+i][k];
      #pragma unroll
      for (int j = 0; j < 4; ++j) bb[j] = Bs[k][tx*4+j];
      #pragma unroll
      for (int i = 0; i < 4; ++i)
        #pragma unroll
        for (int j = 0; j < 4; ++j) acc[i][j] += a[i]*bb[j];
    }
    __syncthreads();
  }

  #pragma unroll
  for (int i = 0; i < 4; ++i){
    const int r = rowBase + ty*4 + i;            // r = b*T + t
    const size_t off = (size_t)r*1024 + colBase + tx*4;  // (b,t, h*128+e)
    if (z == 0){
      float4 v = { acc[i][0]*sc, acc[i][1]*sc, acc[i][2]*sc, acc[i][3]*sc };
      *(float4*)(Q + off) = v;
    } else {
      unsigned short* __restrict__ Outh = (z==1) ? Kh : Vh;
      uint2 pv = { pack_bf16x2(acc[i][0]*sc, acc[i][1]*sc),
                   pack_bf16x2(acc[i][2]*sc, acc[i][3]*sc) };
      *(uint2*)(Outh + off) = pv;
    }
  }
}

// ---------------- kernel 3: gather-attention (batched reduce) ----------------
// One block per (b,t); 8 waves = 8 heads. K/V bf16, layout (b,t,h,e).
#define RSTR 38   // red row stride (f32): (38*r+p)%32 -> 2-way max, free
__global__ __launch_bounds__(512) void attn_kernel(const float* __restrict__ Q,
    const unsigned short* __restrict__ K, const unsigned short* __restrict__ V,
    const int* __restrict__ idx, const float* __restrict__ wts,
    float* __restrict__ out){
  const int bid = blockIdx.x;
  const int bt  = ((bid & 7) << 9) | (bid >> 3);   // XCD swizzle, bijective
  const int b   = bt >> 11;
  const int h   = threadIdx.x >> 6, lane = threadIdx.x & 63;

  __shared__ int   s_koff[P_];
  __shared__ float s_w[P_];
  __shared__ float s_red[NH_ * 32 * RSTR];
  __shared__ float s_a[NH_][40];

  if (threadIdx.x < P_){
    s_koff[threadIdx.x] = idx[bt*P_ + threadIdx.x] << 10;   // element offset ip*1024
    s_w[threadIdx.x]    = wts[bt*P_ + threadIdx.x];
  }
  __syncthreads();

  const size_t rowOff = (size_t)bt*1024 + h*EMB_ + lane*2;
  const float2 q = *(const float2*)(Q + rowOff);
  const unsigned short* __restrict__ Kb = K + (size_t)b*T_*1024 + h*EMB_ + lane*2;
  const unsigned short* __restrict__ Vb = V + (size_t)b*T_*1024 + h*EMB_ + lane*2;

  // ---- Phase A: per-lane partial dots for all 36 points (independent loads) ----
  float pr[P_];
  #pragma unroll
  for (int c = 0; c < 4; ++c){
    unsigned u[9]; int ko[9];
    #pragma unroll
    for (int j = 0; j < 9; ++j) ko[j] = s_koff[c*9+j];
    #pragma unroll
    for (int j = 0; j < 9; ++j) u[j] = *(const unsigned*)(Kb + ko[j]);
    #pragma unroll
    for (int j = 0; j < 9; ++j){
      const float kx = __uint_as_float(u[j] << 16);
      const float ky = __uint_as_float(u[j] & 0xffff0000u);
      pr[c*9+j] = q.x*kx + q.y*ky;
    }
  }

  // ---- Phase B: fold 64->32 lanes, LDS transpose, column sum ----
  #pragma unroll
  for (int p = 0; p < P_; ++p) pr[p] += __shfl_xor(pr[p], 32);

  float* __restrict__ myred = &s_red[h * 32 * RSTR];
  if (lane < 32){
    float* dst = myred + lane * RSTR;
    #pragma unroll
    for (int i = 0; i < 18; ++i){
      float2 v2 = { pr[2*i], pr[2*i+1] };
      *(float2*)(dst + 2*i) = v2;
    }
  }
  const int pcol = (lane < P_) ? lane : 0;
  float s0=0.f, s1=0.f, s2=0.f, s3=0.f;
  #pragma unroll
  for (int r = 0; r < 32; r += 4){
    s0 += myred[(r+0)*RSTR + pcol];
    s1 += myred[(r+1)*RSTR + pcol];
    s2 += myred[(r+2)*RSTR + pcol];
    s3 += myred[(r+3)*RSTR + pcol];
  }
  const float logit = (s0+s1)+(s2+s3);

  // ---- softmax over points (lane-per-point) ----
  float val = (lane < P_) ? logit * s_w[pcol] : -INFINITY;
  float mx = val;
  #pragma unroll
  for (int off = 32; off; off >>= 1) mx = fmaxf(mx, __shfl_xor(mx, off));
  float e = (lane < P_) ? expf(val - mx) : 0.f;
  float s = e;
  #pragma unroll
  for (int off = 32; off; off >>= 1) s += __shfl_xor(s, off);
  if (lane < P_) s_a[h][lane] = e / s;

  // ---- Phase C: PV gather with broadcast weights ----
  float2 acc = {0.f, 0.f};
  #pragma unroll
  for (int c = 0; c < 9; ++c){
    const float4 av = *(const float4*)(&s_a[h][4*c]);
    unsigned u[4]; int ko[4];
    #pragma unroll
    for (int j = 0; j < 4; ++j) ko[j] = s_koff[c*4+j];
    #pragma unroll
    for (int j = 0; j < 4; ++j) u[j] = *(const unsigned*)(Vb + ko[j]);
    const float a0 = av.x, a1 = av.y, a2 = av.z, a3 = av.w;
    acc.x += a0*__uint_as_float(u[0] << 16); acc.y += a0*__uint_as_float(u[0] & 0xffff0000u);
    acc.x += a1*__uint_as_float(u[1] << 16); acc.y += a1*__uint_as_float(u[1] & 0xffff0000u);
    acc.x += a2*__uint_as_float(u[2] << 16); acc.y += a2*__uint_as_float(u[2] & 0xffff0000u);
    acc.x += a3*__uint_as_float(u[3] << 16); acc.y += a3*__uint_as_float(u[3] & 0xffff0000u);
  }
  *(float2*)(out + rowOff) = acc;
}

// ---------------- kernel 4a: output GEMM, split-K partials ----------------
// grid (128 Mtiles, 8 Kchunks); part[kc][4096][128] f32 (reuses Q buffer)
__global__ __launch_bounds__(256) void out_partial_kernel(const float* __restrict__ A,
    const float* __restrict__ Wu, float* __restrict__ part){
  const int tid = threadIdx.x;
  const int tx = tid & 31, ty = tid >> 5;
  const int rowBase = blockIdx.x * 32;
  const int kc = blockIdx.y;
  __shared__ float As[32][36];
  __shared__ float Bs[32][128];
  float acc[4][4] = {};

  const int k0base = kc * 128;
  for (int kk = k0base; kk < k0base + 128; kk += 32){
    {
      const int r = tid >> 3, k4 = tid & 7;
      float4 v = *(const float4*)(A + (size_t)(rowBase+r)*1024 + kk + k4*4);
      *(float4*)(&As[r][k4*4]) = v;
    }
    {
      const int c4 = tid & 31, k0 = tid >> 5;
      #pragma unroll
      for (int i = 0; i < 4; ++i){
        const int k = k0 + 8*i;
        float4 v = *(const float4*)(Wu + (size_t)(kk+k)*128 + c4*4);
        *(float4*)(&Bs[k][c4*4]) = v;
      }
    }
    __syncthreads();
    #pragma unroll 8
    for (int k = 0; k < 32; ++k){
      float a[4], bb[4];
      #pragma unroll
      for (int i = 0; i < 4; ++i) a[i]  = As[ty*4+i][k];
      #pragma unroll
      for (int j = 0; j < 4; ++j) bb[j] = Bs[k][tx*4+j];
      #pragma unroll
      for (int i = 0; i < 4; ++i)
        #pragma unroll
        for (int j = 0; j < 4; ++j) acc[i][j] += a[i]*bb[j];
    }
    __syncthreads();
  }

  float* __restrict__ dst = part + (size_t)kc * (4096*128);
  #pragma unroll
  for (int i = 0; i < 4; ++i){
    const int r = rowBase + ty*4 + i;
    float4 v = { acc[i][0], acc[i][1], acc[i][2], acc[i][3] };
    *(float4*)(dst + (size_t)r*EMB_ + tx*4) = v;
  }
}

// ---------------- kernel 4b: reduce partials + bias ----------------
// 4096*128 f32 = 131072 float4; grid 512 x 256 threads, one float4 each
__global__ __launch_bounds__(256) void out_reduce_kernel(const float* __restrict__ part,
    const float* __restrict__ bu, float* __restrict__ out){
  const int i = blockIdx.x * 256 + threadIdx.x;          // float4 index
  const int c0 = (i & 31) * 4;
  float4 acc = *(const float4*)(bu + c0);
  #pragma unroll
  for (int kc = 0; kc < 8; ++kc){
    float4 v = *(const float4*)(part + (size_t)kc*(4096*128) + (size_t)i*4);
    acc.x += v.x; acc.y += v.y; acc.z += v.z; acc.w += v.w;
  }
  *(float4*)(out + (size_t)i*4) = acc;
}

// ---------------- launch ----------------
extern "C" void kernel_launch(void* const* d_in, const int* in_sizes, int n_in,
                              void* d_out, int out_size, void* d_ws, size_t ws_size,
                              hipStream_t stream){
  (void)in_sizes; (void)n_in; (void)out_size; (void)ws_size;
  const float* x    = (const float*)d_in[0];
  const float* sp   = (const float*)d_in[1];
  const float* mvl  = (const float*)d_in[2];
  const float* Wq   = (const float*)d_in[3];
  const float* Wk   = (const float*)d_in[4];
  const float* Wv   = (const float*)d_in[5];
  const float* Wu   = (const float*)d_in[6];
  const float* bu   = (const float*)d_in[7];
  float* out = (float*)d_out;

  const size_t n = (size_t)B_*NH_*T_*EMB_;           // 4,194,304
  float*          Q    = (float*)d_ws;               // n f32 (reused as split-K partials)
  unsigned short* Kh   = (unsigned short*)(Q + n);   // n bf16
  unsigned short* Vh   = Kh + n;                     // n bf16
  float*          attn = (float*)(Vh + n);           // n f32, (b,t,h*e)
  int*            idxb = (int*)(attn + n);
  float*          wb   = (float*)(idxb + (size_t)B_*T_*P_);
  float*          part = Q;                          // 8 * 4096 * 128 f32 == n

  idx_weights_kernel<<<B_*T_, 64, 0, stream>>>(sp, mvl, idxb, wb);
  qkv_kernel<<<dim3(16, 64, 3), 256, 0, stream>>>(x, Wq, Wk, Wv, Q, Kh, Vh);
  attn_kernel<<<B_*T_, 512, 0, stream>>>(Q, Kh, Vh, idxb, wb, attn);
  out_partial_kernel<<<dim3(128, 8), 256, 0, stream>>>(attn, Wu, part);
  out_reduce_kernel<<<512, 256, 0, stream>>>(part, bu, out);
}

// Round 7
// 113.060 us; speedup vs baseline: 2.1453x; 1.1470x over previous
//
#include <hip/hip_runtime.h>
#include <math.h>

#define B_    2
#define T_    2048
#define EMB_  128
#define NH_   8
#define M_    9
#define P_    36
#define GADD_ 2

typedef __attribute__((ext_vector_type(8))) short bf16x8;
typedef __attribute__((ext_vector_type(4))) float f32x4;

// ---------------- Threefry-2x32 (jax PRNG) ----------------
__device__ __forceinline__ unsigned rotl32(unsigned x, int r){ return (x<<r)|(x>>(32-r)); }

struct U2 { unsigned x, y; };

__device__ __forceinline__ U2 tf2x32(U2 key, U2 ctr){
  unsigned ks[3] = { key.x, key.y, key.x ^ key.y ^ 0x1BD11BDAu };
  unsigned x0 = ctr.x + ks[0], x1 = ctr.y + ks[1];
  const int rotA[4] = {13,15,26,6}, rotB[4] = {17,29,16,24};
  #pragma unroll
  for (int r = 0; r < 5; ++r){
    const int* rr = (r & 1) ? rotB : rotA;
    #pragma unroll
    for (int i = 0; i < 4; ++i){ x0 += x1; x1 = rotl32(x1, rr[i]); x1 ^= x0; }
    x0 += ks[(r+1)%3];
    x1 += ks[(r+2)%3] + (unsigned)(r+1);
  }
  return { x0, x1 };
}

// randint(key(42),(B,T,M,GADD),0,T), partitionable threefry path.
__device__ unsigned glob_rand(unsigned f){
  U2 k2 = tf2x32({0u, 42u}, {0u, 1u});
  U2 o  = tf2x32(k2, {0u, f});
  return (o.x ^ o.y) & (unsigned)(T_-1);
}

__device__ __forceinline__ unsigned pack_bf16x2(float a, float b){
  unsigned ua = __float_as_uint(a), ub = __float_as_uint(b);
  ua = ua + 0x7fffu + ((ua >> 16) & 1u);
  ub = ub + 0x7fffu + ((ub >> 16) & 1u);
  return (ua >> 16) | (ub & 0xffff0000u);
}
__device__ __forceinline__ unsigned short bf16r(float f){
  unsigned u = __float_as_uint(f);
  u = u + 0x7fffu + ((u >> 16) & 1u);
  return (unsigned short)(u >> 16);
}

// ---------------- convert kernels ----------------
// x (524288 f32) -> bf16, 4 elems/thread
__global__ __launch_bounds__(256) void xconv_kernel(const float* __restrict__ x,
                                                    unsigned short* __restrict__ xh){
  const int i = (blockIdx.x*256 + threadIdx.x)*4;
  float4 v = *(const float4*)(x + i);
  uint2 p = { pack_bf16x2(v.x, v.y), pack_bf16x2(v.z, v.w) };
  *(uint2*)(xh + i) = p;
}

// transpose+convert: A[R][C] f32 -> out[C][R] bf16, scaled. grid (C/32, R/32, nz)
__global__ __launch_bounds__(256) void tconv_kernel(const float* __restrict__ A0,
    const float* __restrict__ A1, const float* __restrict__ A2,
    unsigned short* __restrict__ out, int R, int C, float s01, float s2){
  const float* __restrict__ A = (blockIdx.z==0) ? A0 : (blockIdx.z==1) ? A1 : A2;
  const float scale = (blockIdx.z < 2) ? s01 : s2;
  unsigned short* __restrict__ o = out + (size_t)blockIdx.z * R * C;
  __shared__ float tile[32][33];
  const int c0 = blockIdx.x*32, r0 = blockIdx.y*32;
  const int tx = threadIdx.x & 31, ty = threadIdx.x >> 5;
  #pragma unroll
  for (int i = 0; i < 32; i += 8)
    tile[ty+i][tx] = A[(size_t)(r0+ty+i)*C + c0+tx];
  __syncthreads();
  #pragma unroll
  for (int i = 0; i < 32; i += 8)
    o[(size_t)(c0+ty+i)*R + (r0+tx)] = bf16r(tile[tx][ty+i] * scale);
}

// ---------------- kernel 1: indices + weights ----------------
__global__ void idx_weights_kernel(const float* __restrict__ sp, const float* __restrict__ mvals,
                                   int* __restrict__ idx_out, float* __restrict__ w_out){
  const int bt = blockIdx.x;
  const int t  = bt & (T_-1);
  const int p  = threadIdx.x;
  __shared__ int   s_idx[P_];
  __shared__ float s_dens[P_][M_];
  __shared__ float s_col[M_];

  const float dil  = sp[0];
  const float xs   = sp[1] + 2.0f;
  const float sigma = xs + log1pf(expf(-xs)) + 1e-7f;

  if (p < P_){
    const int m = p >> 2, j = p & 3;
    const float mean = fminf(fmaxf((float)t + (float)(m-4)*dil, 0.f), (float)(T_-1));
    int id;
    if      (j == 0) id = (int)floorf(mean);
    else if (j == 1) id = min((int)floorf(mean) + 1, T_-1);
    else {
      const unsigned f = ((unsigned)bt * M_ + (unsigned)m) * GADD_ + (unsigned)(j-2);
      id = (int)glob_rand(f);
    }
    s_idx[p] = id;
  }
  __syncthreads();
  if (p < P_){
    const int myid = s_idx[p];
    bool dup = false;
    for (int q = 0; q < p; ++q) dup |= (s_idx[q] == myid);
    const float pf = (float)myid;
    #pragma unroll
    for (int m = 0; m < M_; ++m){
      const float mean = fminf(fmaxf((float)t + (float)(m-4)*dil, 0.f), (float)(T_-1));
      const float d = (pf - mean) / sigma;
      s_dens[p][m] = dup ? 0.f : expf(-0.5f * d * d);
    }
  }
  __syncthreads();
  if (p < M_){
    float s = 0.f;
    for (int q = 0; q < P_; ++q) s += s_dens[q][p];
    s_col[p] = s;
  }
  __syncthreads();
  if (p < P_){
    float w = 0.f;
    #pragma unroll
    for (int m = 0; m < M_; ++m) w += s_dens[p][m] / s_col[m] * mvals[m];
    idx_out[bt*P_ + p] = s_idx[p];
    w_out[bt*P_ + p]   = w;
  }
}

// ---------------- kernel 2: QKV via MFMA ----------------
// D(4096x1024) = xh(4096x128) @ W(128x1024); WT[z][n][k] bf16 (scale baked).
// grid (16, 64, 3), 256 thr = 4 waves; wave: 16M x 64N, K=128.
__global__ __launch_bounds__(256) void qkv_mfma_kernel(const unsigned short* __restrict__ xh,
    const unsigned short* __restrict__ WT,
    float* __restrict__ Q, unsigned short* __restrict__ Kh, unsigned short* __restrict__ Vh){
  const int z  = blockIdx.z;
  const int w  = threadIdx.x >> 6, l = threadIdx.x & 63;
  const int m0 = blockIdx.y*64 + w*16;
  const int n0 = blockIdx.x*64;
  const int lr = l & 15, lk = l >> 4;

  const unsigned short* __restrict__ WTz = WT + (size_t)z * 1024 * 128;

  bf16x8 a[4];
  #pragma unroll
  for (int kc = 0; kc < 4; ++kc)
    a[kc] = *(const bf16x8*)(xh + (size_t)(m0+lr)*128 + kc*32 + lk*8);

  f32x4 acc[4] = {};
  #pragma unroll
  for (int nf = 0; nf < 4; ++nf){
    #pragma unroll
    for (int kc = 0; kc < 4; ++kc){
      bf16x8 b = *(const bf16x8*)(WTz + (size_t)(n0+nf*16+lr)*128 + kc*32 + lk*8);
      acc[nf] = __builtin_amdgcn_mfma_f32_16x16x32_bf16(a[kc], b, acc[nf], 0, 0, 0);
    }
  }
  #pragma unroll
  for (int nf = 0; nf < 4; ++nf){
    const int col = n0 + nf*16 + lr;
    #pragma unroll
    for (int r = 0; r < 4; ++r){
      const size_t off = (size_t)(m0 + lk*4 + r)*1024 + col;
      if (z == 0) Q[off] = acc[nf][r];
      else if (z == 1) Kh[off] = bf16r(acc[nf][r]);
      else             Vh[off] = bf16r(acc[nf][r]);
    }
  }
}

// ---------------- kernel 3: gather-attention (batched reduce), bf16 out ----------------
#define RSTR 38
__global__ __launch_bounds__(512) void attn_kernel(const float* __restrict__ Q,
    const unsigned short* __restrict__ K, const unsigned short* __restrict__ V,
    const int* __restrict__ idx, const float* __restrict__ wts,
    unsigned short* __restrict__ outh){
  const int bid = blockIdx.x;
  const int bt  = ((bid & 7) << 9) | (bid >> 3);   // XCD swizzle, bijective
  const int b   = bt >> 11;
  const int h   = threadIdx.x >> 6, lane = threadIdx.x & 63;

  __shared__ int   s_koff[P_];
  __shared__ float s_w[P_];
  __shared__ float s_red[NH_ * 32 * RSTR];
  __shared__ float s_a[NH_][40];

  if (threadIdx.x < P_){
    s_koff[threadIdx.x] = idx[bt*P_ + threadIdx.x] << 10;
    s_w[threadIdx.x]    = wts[bt*P_ + threadIdx.x];
  }
  __syncthreads();

  const size_t rowOff = (size_t)bt*1024 + h*EMB_ + lane*2;
  const float2 q = *(const float2*)(Q + rowOff);
  const unsigned short* __restrict__ Kb = K + (size_t)b*T_*1024 + h*EMB_ + lane*2;
  const unsigned short* __restrict__ Vb = V + (size_t)b*T_*1024 + h*EMB_ + lane*2;

  float pr[P_];
  #pragma unroll
  for (int c = 0; c < 4; ++c){
    unsigned u[9]; int ko[9];
    #pragma unroll
    for (int j = 0; j < 9; ++j) ko[j] = s_koff[c*9+j];
    #pragma unroll
    for (int j = 0; j < 9; ++j) u[j] = *(const unsigned*)(Kb + ko[j]);
    #pragma unroll
    for (int j = 0; j < 9; ++j){
      const float kx = __uint_as_float(u[j] << 16);
      const float ky = __uint_as_float(u[j] & 0xffff0000u);
      pr[c*9+j] = q.x*kx + q.y*ky;
    }
  }

  #pragma unroll
  for (int p = 0; p < P_; ++p) pr[p] += __shfl_xor(pr[p], 32);

  float* __restrict__ myred = &s_red[h * 32 * RSTR];
  if (lane < 32){
    float* dst = myred + lane * RSTR;
    #pragma unroll
    for (int i = 0; i < 18; ++i){
      float2 v2 = { pr[2*i], pr[2*i+1] };
      *(float2*)(dst + 2*i) = v2;
    }
  }
  const int pcol = (lane < P_) ? lane : 0;
  float s0=0.f, s1=0.f, s2=0.f, s3=0.f;
  #pragma unroll
  for (int r = 0; r < 32; r += 4){
    s0 += myred[(r+0)*RSTR + pcol];
    s1 += myred[(r+1)*RSTR + pcol];
    s2 += myred[(r+2)*RSTR + pcol];
    s3 += myred[(r+3)*RSTR + pcol];
  }
  const float logit = (s0+s1)+(s2+s3);

  float val = (lane < P_) ? logit * s_w[pcol] : -INFINITY;
  float mx = val;
  #pragma unroll
  for (int off = 32; off; off >>= 1) mx = fmaxf(mx, __shfl_xor(mx, off));
  float e = (lane < P_) ? expf(val - mx) : 0.f;
  float s = e;
  #pragma unroll
  for (int off = 32; off; off >>= 1) s += __shfl_xor(s, off);
  if (lane < P_) s_a[h][lane] = e / s;

  float2 acc = {0.f, 0.f};
  #pragma unroll
  for (int c = 0; c < 9; ++c){
    const float4 av = *(const float4*)(&s_a[h][4*c]);
    unsigned u[4]; int ko[4];
    #pragma unroll
    for (int j = 0; j < 4; ++j) ko[j] = s_koff[c*4+j];
    #pragma unroll
    for (int j = 0; j < 4; ++j) u[j] = *(const unsigned*)(Vb + ko[j]);
    const float a0 = av.x, a1 = av.y, a2 = av.z, a3 = av.w;
    acc.x += a0*__uint_as_float(u[0] << 16); acc.y += a0*__uint_as_float(u[0] & 0xffff0000u);
    acc.x += a1*__uint_as_float(u[1] << 16); acc.y += a1*__uint_as_float(u[1] & 0xffff0000u);
    acc.x += a2*__uint_as_float(u[2] << 16); acc.y += a2*__uint_as_float(u[2] & 0xffff0000u);
    acc.x += a3*__uint_as_float(u[3] << 16); acc.y += a3*__uint_as_float(u[3] & 0xffff0000u);
  }
  *(unsigned*)(outh + rowOff) = pack_bf16x2(acc.x, acc.y);
}

// ---------------- kernel 4: output GEMM via MFMA + bias ----------------
// out(4096x128) = attnh(4096x1024) @ Wu(1024x128) + bu; WuT[128][1024] bf16.
// grid (4, 64), 256 thr = 4 waves; wave: 16M x 32N, K=1024.
__global__ __launch_bounds__(256) void out_mfma_kernel(const unsigned short* __restrict__ Ah,
    const unsigned short* __restrict__ WuT, const float* __restrict__ bu,
    float* __restrict__ out){
  const int w  = threadIdx.x >> 6, l = threadIdx.x & 63;
  const int m0 = blockIdx.y*64 + w*16;
  const int n0 = blockIdx.x*32;
  const int lr = l & 15, lk = l >> 4;

  const unsigned short* __restrict__ arow = Ah  + (size_t)(m0+lr)*1024 + lk*8;
  const unsigned short* __restrict__ b0   = WuT + (size_t)(n0+lr)*1024 + lk*8;
  const unsigned short* __restrict__ b1   = b0 + 16*1024;

  f32x4 acc0 = {}, acc1 = {};
  #pragma unroll 4
  for (int kc = 0; kc < 32; ++kc){
    bf16x8 a  = *(const bf16x8*)(arow + kc*32);
    bf16x8 bb0 = *(const bf16x8*)(b0 + kc*32);
    bf16x8 bb1 = *(const bf16x8*)(b1 + kc*32);
    acc0 = __builtin_amdgcn_mfma_f32_16x16x32_bf16(a, bb0, acc0, 0, 0, 0);
    acc1 = __builtin_amdgcn_mfma_f32_16x16x32_bf16(a, bb1, acc1, 0, 0, 0);
  }
  const int c0 = n0 + lr, c1 = c0 + 16;
  const float bias0 = bu[c0], bias1 = bu[c1];
  #pragma unroll
  for (int r = 0; r < 4; ++r){
    const size_t row = (size_t)(m0 + lk*4 + r);
    out[row*128 + c0] = acc0[r] + bias0;
    out[row*128 + c1] = acc1[r] + bias1;
  }
}

// ---------------- launch ----------------
extern "C" void kernel_launch(void* const* d_in, const int* in_sizes, int n_in,
                              void* d_out, int out_size, void* d_ws, size_t ws_size,
                              hipStream_t stream){
  (void)in_sizes; (void)n_in; (void)out_size; (void)ws_size;
  const float* x    = (const float*)d_in[0];
  const float* sp   = (const float*)d_in[1];
  const float* mvl  = (const float*)d_in[2];
  const float* Wq   = (const float*)d_in[3];
  const float* Wk   = (const float*)d_in[4];
  const float* Wv   = (const float*)d_in[5];
  const float* Wu   = (const float*)d_in[6];
  const float* bu   = (const float*)d_in[7];
  float* out = (float*)d_out;

  const size_t n = (size_t)B_*NH_*T_*EMB_;             // 4,194,304
  float*          Q     = (float*)d_ws;                // n f32
  unsigned short* Kh    = (unsigned short*)(Q + n);    // n bf16
  unsigned short* Vh    = Kh + n;                      // n bf16
  unsigned short* attnh = Vh + n;                      // n bf16 (b,t,h*e)
  unsigned short* xh    = attnh + n;                   // 524288 bf16
  unsigned short* WT    = xh + (size_t)B_*T_*EMB_;     // 3*131072 bf16
  unsigned short* WuT   = WT + 3*131072;               // 131072 bf16
  int*            idxb  = (int*)(WuT + 131072);
  float*          wb    = (float*)(idxb + (size_t)B_*T_*P_);

  const float sc = 0.29730177875068026f; // 128^-0.25

  xconv_kernel<<<512, 256, 0, stream>>>(x, xh);
  tconv_kernel<<<dim3(32, 4, 3), 256, 0, stream>>>(Wq, Wk, Wv, WT, 128, 1024, sc, 1.0f);
  tconv_kernel<<<dim3(4, 32, 1), 256, 0, stream>>>(Wu, Wu, Wu, WuT, 1024, 128, 1.0f, 1.0f);
  idx_weights_kernel<<<B_*T_, 64, 0, stream>>>(sp, mvl, idxb, wb);
  qkv_mfma_kernel<<<dim3(16, 64, 3), 256, 0, stream>>>(xh, WT, Q, Kh, Vh);
  attn_kernel<<<B_*T_, 512, 0, stream>>>(Q, Kh, Vh, idxb, wb, attnh);
  out_mfma_kernel<<<dim3(4, 64), 256, 0, stream>>>(attnh, WuT, bu, out);
}